// Round 2
// baseline (371.822 us; speedup 1.0000x reference)
//
#include <hip/hip_runtime.h>

#define D_EMB 768
#define NH 12
#define DK 64
#define NB 2
#define SS 4096
#define E3 (3*D_EMB)   // 2304
#define MM (NB*SS)     // 8192

typedef unsigned short u16;
typedef __attribute__((ext_vector_type(8))) __bf16 bf16x8;
typedef __attribute__((ext_vector_type(4))) float f32x4;
typedef __attribute__((ext_vector_type(4))) unsigned int u32x4;

static __device__ __forceinline__ u16 f2bf(float f) {
  unsigned u = __builtin_bit_cast(unsigned, f);
  u += 0x7fffu + ((u >> 16) & 1u);          // round-to-nearest-even
  return (u16)(u >> 16);
}
static __device__ __forceinline__ f32x4 mfma16(bf16x8 a, bf16x8 b, f32x4 c) {
  return __builtin_amdgcn_mfma_f32_16x16x32_bf16(a, b, c, 0, 0, 0);
}
static __device__ __forceinline__ float exp2_fast(float x) {
#if __has_builtin(__builtin_amdgcn_exp2f)
  return __builtin_amdgcn_exp2f(x);
#else
  return __builtin_exp2f(x);
#endif
}
static __device__ __forceinline__ float rcp_fast(float x) {
#if __has_builtin(__builtin_amdgcn_rcpf)
  return __builtin_amdgcn_rcpf(x);
#else
  return 1.f / x;
#endif
}
static __device__ __forceinline__ void gload_lds16(const u16* g, u16* l) {
  __builtin_amdgcn_global_load_lds((const __attribute__((address_space(1))) void*)g,
                                   (__attribute__((address_space(3))) void*)l, 16, 0, 0);
}

// ---------------- cast fp32 -> bf16, elementwise ----------------
__global__ __launch_bounds__(256) void cast_kernel(const float* __restrict__ in,
                                                   u16* __restrict__ out, int n) {
  int i = (blockIdx.x * 256 + threadIdx.x) * 4;
  if (i + 3 < n) {
    float4 v = *(const float4*)(in + i);
    out[i + 0] = f2bf(v.x);
    out[i + 1] = f2bf(v.y);
    out[i + 2] = f2bf(v.z);
    out[i + 3] = f2bf(v.w);
  }
}

// -------- transpose + cast weights: WT[n][k] = W[k][n] * scale --------
__global__ __launch_bounds__(256) void transpose_cast_w(const float* __restrict__ W,
                                                        u16* __restrict__ WT, float scale) {
  __shared__ float tile[32][33];
  int kb = blockIdx.y * 32, nb = blockIdx.x * 32;
  int tx = threadIdx.x, ty = threadIdx.y;
#pragma unroll
  for (int i = 0; i < 4; i++)
    tile[ty + i * 8][tx] = W[(size_t)(kb + ty + i * 8) * D_EMB + nb + tx];
  __syncthreads();
#pragma unroll
  for (int i = 0; i < 4; i++)
    WT[(size_t)(nb + ty + i * 8) * D_EMB + kb + tx] = f2bf(tile[tx][ty + i * 8] * scale);
}

// -------- transpose V (bf16): VT[(b*12+h)*64 + d][s] = QKV[b*4096+s][1536+h*64+d] --------
__global__ __launch_bounds__(256) void transpose_v(const u16* __restrict__ QKV,
                                                   u16* __restrict__ VT) {
  __shared__ u16 tile[32][33];
  int bh = blockIdx.z;
  int b = bh / NH, h = bh % NH;
  int sb = blockIdx.x * 32, db = blockIdx.y * 32;
  int tx = threadIdx.x, ty = threadIdx.y;
  const u16* src = QKV + (size_t)(b * SS) * E3 + 2 * D_EMB + h * DK;
  u16* dst = VT + (size_t)bh * DK * SS;
#pragma unroll
  for (int i = 0; i < 4; i++)
    tile[ty + i * 8][tx] = src[(size_t)(sb + ty + i * 8) * E3 + db + tx];
  __syncthreads();
#pragma unroll
  for (int i = 0; i < 4; i++)
    dst[(size_t)(db + ty + i * 8) * SS + sb + tx] = tile[tx][ty + i * 8];
}

// ---------------- bf16 GEMM, B given transposed: C[M][N] = A[M][K] @ Bt[N][K]^T ----------------
// block 256 = 4 waves (2x2), 128x128 tile, BK=32, mfma 16x16x32, global_load_lds staging
template <int OUTF32>
__global__ __launch_bounds__(256) void gemm_bt(const u16* __restrict__ A,
                                               const u16* __restrict__ Bt,
                                               void* __restrict__ Cout,
                                               int M, int N, int K, float scale) {
  __shared__ __align__(16) u16 As[128 * 32];
  __shared__ __align__(16) u16 Bs[128 * 32];
  int tid = threadIdx.x;
  int wave = tid >> 6, lane = tid & 63;
  int g = lane >> 4, nIdx = lane & 15;
  int m0 = blockIdx.y * 128, n0 = blockIdx.x * 128;
  int wm = (wave >> 1) * 64, wn = (wave & 1) * 64;

  f32x4 acc[4][4] = {};

  int row = tid >> 2, co = (tid & 3) * 8;         // LDS dest = base + tid*16B (wave-uniform + lane*16)
  int row2 = row + 64;

  for (int k0 = 0; k0 < K; k0 += 32) {
    __syncthreads();
    gload_lds16(A  + (size_t)(m0 + row)  * K + k0 + co, As + row  * 32 + co);
    gload_lds16(Bt + (size_t)(n0 + row)  * K + k0 + co, Bs + row  * 32 + co);
    gload_lds16(A  + (size_t)(m0 + row2) * K + k0 + co, As + row2 * 32 + co);
    gload_lds16(Bt + (size_t)(n0 + row2) * K + k0 + co, Bs + row2 * 32 + co);
    __syncthreads();

    bf16x8 af[4], bfr[4];
#pragma unroll
    for (int i = 0; i < 4; i++)
      af[i] = *(const bf16x8*)(As + (wm + i * 16 + nIdx) * 32 + g * 8);
#pragma unroll
    for (int j = 0; j < 4; j++)
      bfr[j] = *(const bf16x8*)(Bs + (wn + j * 16 + nIdx) * 32 + g * 8);
#pragma unroll
    for (int i = 0; i < 4; i++)
#pragma unroll
      for (int j = 0; j < 4; j++)
        acc[i][j] = mfma16(af[i], bfr[j], acc[i][j]);
  }

#pragma unroll
  for (int i = 0; i < 4; i++)
#pragma unroll
    for (int j = 0; j < 4; j++)
#pragma unroll
      for (int r = 0; r < 4; r++) {
        int rr = m0 + wm + i * 16 + g * 4 + r;
        int cc = n0 + wn + j * 16 + nIdx;
        float v = acc[i][j][r] * scale;
        if (OUTF32)
          ((float*)Cout)[(size_t)rr * N + cc] = v;
        else
          ((u16*)Cout)[(size_t)rr * N + cc] = f2bf(v);
      }
}

// ---------------- flash attention (S^T formulation, register P exchange) ----------------
// grid (S/64, NH, B), block 256 (4 waves, 16 q-rows each)
// Q was pre-scaled by 0.125*log2(e): scores are in log2 domain, P = exp2(S).
__global__ __launch_bounds__(256) void flash(const u16* __restrict__ QKV,
                                             const u16* __restrict__ VT,
                                             u16* __restrict__ O) {
  __shared__ __align__(16) u16 Ks[64 * 72];      // [kv][d], pad 8
  __shared__ __align__(16) u16 Vs[64 * 72];      // [d][kv], pad 8

  int b = blockIdx.z, h = blockIdx.y, qt = blockIdx.x;
  int tid = threadIdx.x, wave = tid >> 6, lane = tid & 63;
  int Q = lane >> 4, n = lane & 15;
  int hiQ = lane & 32;                            // (Q>>1) selector

  const u16* Qbase = QKV + (size_t)(b * SS + qt * 64) * E3 + h * DK;
  const u16* Kbase = QKV + (size_t)(b * SS) * E3 + D_EMB + h * DK;
  const u16* VTbase = VT + (size_t)(b * NH + h) * DK * SS;

  bf16x8 qf[2];
#pragma unroll
  for (int km = 0; km < 2; km++)
    qf[km] = *(const bf16x8*)(Qbase + (size_t)(wave * 16 + n) * E3 + km * 32 + Q * 8);

  f32x4 o_acc[4] = {};
  f32x4 l_acc = {};
  u32x4 onev = {0x3F803F80u, 0x3F803F80u, 0x3F803F80u, 0x3F803F80u};
  bf16x8 aone = __builtin_bit_cast(bf16x8, onev);  // bf16 1.0 x8

  // bpermute byte addrs: srcQ = (Q&1)*2 (+1 for hp>=2), same n
  int addrA = ((lane & 16) << 3) | (n << 2);
  int addrB = addrA + 64;

  int srow = tid >> 3, sco = (tid & 7) * 8;
  int srow2 = srow + 32;

  for (int kt = 0; kt < SS / 64; kt++) {
    __syncthreads();
    {
      uint4 k0 = *(const uint4*)(Kbase + (size_t)(kt * 64 + srow) * E3 + sco);
      uint4 v0 = *(const uint4*)(VTbase + (size_t)srow * SS + kt * 64 + sco);
      uint4 k1 = *(const uint4*)(Kbase + (size_t)(kt * 64 + srow2) * E3 + sco);
      uint4 v1 = *(const uint4*)(VTbase + (size_t)srow2 * SS + kt * 64 + sco);
      *(uint4*)(Ks + srow * 72 + sco) = k0;
      *(uint4*)(Vs + srow * 72 + sco) = v0;
      *(uint4*)(Ks + srow2 * 72 + sco) = k1;
      *(uint4*)(Vs + srow2 * 72 + sco) = v1;
    }
    __syncthreads();

    // S^T = K Q^T per 16-kv block j: lane holds S[q=n][kv=j*16+Q*4+r]
    // P = exp2(S^T), packed to bf16 pairs pk[j][h] = kv pair (j*8 + Q*2 + h)
    int pk[4][2];
#pragma unroll
    for (int j = 0; j < 4; j++) {
      bf16x8 kf0 = *(const bf16x8*)(Ks + (j * 16 + n) * 72 + Q * 8);
      bf16x8 kf1 = *(const bf16x8*)(Ks + (j * 16 + n) * 72 + 32 + Q * 8);
      f32x4 t = {};
      t = mfma16(kf0, qf[0], t);
      t = mfma16(kf1, qf[1], t);
      float p0 = exp2_fast(t[0]);
      float p1 = exp2_fast(t[1]);
      float p2 = exp2_fast(t[2]);
      float p3 = exp2_fast(t[3]);
      // pack top halves (truncate to bf16): low16 = even kv
      pk[j][0] = __builtin_amdgcn_perm(__builtin_bit_cast(unsigned, p1),
                                       __builtin_bit_cast(unsigned, p0), 0x07060302u);
      pk[j][1] = __builtin_amdgcn_perm(__builtin_bit_cast(unsigned, p3),
                                       __builtin_bit_cast(unsigned, p2), 0x07060302u);
    }

    // Exchange: build P^T B-frags (m=0: kv 0..31, m=1: kv 32..63)
    // slot (m,hp): value = pk[2m + (Q>>1)][hp&1] from lane ((Q&1)*2 + (hp>>1))*16 + n
    u32x4 bw0, bw1;
#pragma unroll
    for (int hp = 0; hp < 4; hp++) {
      int ad = (hp < 2) ? addrA : addrB;
      int h2 = hp & 1;
      int lo0 = __builtin_amdgcn_ds_bpermute(ad, pk[0][h2]);
      int hi0 = __builtin_amdgcn_ds_bpermute(ad, pk[1][h2]);
      int lo1 = __builtin_amdgcn_ds_bpermute(ad, pk[2][h2]);
      int hi1 = __builtin_amdgcn_ds_bpermute(ad, pk[3][h2]);
      bw0[hp] = (unsigned)(hiQ ? hi0 : lo0);
      bw1[hp] = (unsigned)(hiQ ? hi1 : lo1);
    }
    bf16x8 B0 = __builtin_bit_cast(bf16x8, bw0);
    bf16x8 B1 = __builtin_bit_cast(bf16x8, bw1);

    // row sums via ones-MFMA (consistent with bf16 P)
    l_acc = mfma16(aone, B0, l_acc);
    l_acc = mfma16(aone, B1, l_acc);

    // O^T += V^T P^T : lane holds O[q=n][d = dt*16 + Q*4 + r]
#pragma unroll
    for (int dt = 0; dt < 4; dt++) {
      bf16x8 vf0 = *(const bf16x8*)(Vs + (dt * 16 + n) * 72 + Q * 8);
      bf16x8 vf1 = *(const bf16x8*)(Vs + (dt * 16 + n) * 72 + 32 + Q * 8);
      o_acc[dt] = mfma16(vf0, B0, o_acc[dt]);
      o_acc[dt] = mfma16(vf1, B1, o_acc[dt]);
    }
  }

  float rl = rcp_fast(l_acc[0]);
  u16* Obase = O + (size_t)(b * SS + qt * 64 + wave * 16 + n) * D_EMB + h * DK;
#pragma unroll
  for (int dt = 0; dt < 4; dt++) {
    unsigned w0 = (unsigned)f2bf(o_acc[dt][0] * rl) | ((unsigned)f2bf(o_acc[dt][1] * rl) << 16);
    unsigned w1 = (unsigned)f2bf(o_acc[dt][2] * rl) | ((unsigned)f2bf(o_acc[dt][3] * rl) << 16);
    *(unsigned*)(Obase + dt * 16 + Q * 4) = w0;
    *(unsigned*)(Obase + dt * 16 + Q * 4 + 2) = w1;
  }
}

extern "C" void kernel_launch(void* const* d_in, const int* in_sizes, int n_in,
                              void* d_out, int out_size, void* d_ws, size_t ws_size,
                              hipStream_t stream) {
  const float* X  = (const float*)d_in[0];
  const float* Wq = (const float*)d_in[1];
  const float* Wk = (const float*)d_in[2];
  const float* Wv = (const float*)d_in[3];
  const float* Wo = (const float*)d_in[4];
  float* out = (float*)d_out;

  u16* Xb    = (u16*)d_ws;                         // MM*D_EMB
  u16* WTqkv = Xb + (size_t)MM * D_EMB;            // E3*D_EMB
  u16* WoT   = WTqkv + (size_t)E3 * D_EMB;         // D_EMB*D_EMB
  u16* QKV   = WoT + (size_t)D_EMB * D_EMB;        // MM*E3
  u16* VT    = QKV + (size_t)MM * E3;               // NB*NH*DK*SS
  u16* Ob    = VT + (size_t)NB * NH * DK * SS;     // MM*D_EMB

  dim3 tb(32, 8);
  cast_kernel<<<(MM * D_EMB) / 1024, 256, 0, stream>>>(X, Xb, MM * D_EMB);
  // fold 1/sqrt(dk) * log2(e) into Wq: scores come out in log2 domain
  transpose_cast_w<<<dim3(24, 24), tb, 0, stream>>>(Wq, WTqkv, 0.125f * 1.4426950408889634f);
  transpose_cast_w<<<dim3(24, 24), tb, 0, stream>>>(Wk, WTqkv + (size_t)D_EMB * D_EMB, 1.0f);
  transpose_cast_w<<<dim3(24, 24), tb, 0, stream>>>(Wv, WTqkv + (size_t)2 * D_EMB * D_EMB, 1.0f);
  transpose_cast_w<<<dim3(24, 24), tb, 0, stream>>>(Wo, WoT, 1.0f);

  gemm_bt<0><<<dim3(E3 / 128, MM / 128), 256, 0, stream>>>(Xb, WTqkv, (void*)QKV,
                                                           MM, E3, D_EMB, 1.0f);
  transpose_v<<<dim3(SS / 32, 2, NB * NH), tb, 0, stream>>>(QKV, VT);
  flash<<<dim3(SS / 64, NH, NB), 256, 0, stream>>>(QKV, VT, Ob);
  gemm_bt<1><<<dim3(D_EMB / 128, MM / 128), 256, 0, stream>>>(Ob, WoT, (void*)out,
                                                              MM, D_EMB, D_EMB, 1.0f);
}

// Round 3
// 284.365 us; speedup vs baseline: 1.3075x; 1.3075x over previous
//
#include <hip/hip_runtime.h>

#define D_EMB 768
#define NH 12
#define DK 64
#define NB 2
#define SS 4096
#define E3 (3*D_EMB)   // 2304
#define MM (NB*SS)     // 8192

typedef unsigned short u16;
typedef __attribute__((ext_vector_type(8))) __bf16 bf16x8;
typedef __attribute__((ext_vector_type(4))) float f32x4;
typedef __attribute__((ext_vector_type(4))) unsigned int u32x4;

static __device__ __forceinline__ u16 f2bf(float f) {
  unsigned u = __builtin_bit_cast(unsigned, f);
  u += 0x7fffu + ((u >> 16) & 1u);          // round-to-nearest-even
  return (u16)(u >> 16);
}
static __device__ __forceinline__ f32x4 mfma16(bf16x8 a, bf16x8 b, f32x4 c) {
  return __builtin_amdgcn_mfma_f32_16x16x32_bf16(a, b, c, 0, 0, 0);
}
static __device__ __forceinline__ float exp2_fast(float x) {
#if __has_builtin(__builtin_amdgcn_exp2f)
  return __builtin_amdgcn_exp2f(x);
#else
  return __builtin_exp2f(x);
#endif
}
static __device__ __forceinline__ float rcp_fast(float x) {
#if __has_builtin(__builtin_amdgcn_rcpf)
  return __builtin_amdgcn_rcpf(x);
#else
  return 1.f / x;
#endif
}
static __device__ __forceinline__ void gload_lds16(const u16* g, u16* l) {
  __builtin_amdgcn_global_load_lds((const __attribute__((address_space(1))) void*)g,
                                   (__attribute__((address_space(3))) void*)l, 16, 0, 0);
}

// ---------------- cast fp32 -> bf16, elementwise ----------------
__global__ __launch_bounds__(256) void cast_kernel(const float* __restrict__ in,
                                                   u16* __restrict__ out, int n) {
  int i = (blockIdx.x * 256 + threadIdx.x) * 4;
  if (i + 3 < n) {
    float4 v = *(const float4*)(in + i);
    out[i + 0] = f2bf(v.x);
    out[i + 1] = f2bf(v.y);
    out[i + 2] = f2bf(v.z);
    out[i + 3] = f2bf(v.w);
  }
}

// -------- transpose + cast weights: WT[n][k] = W[k][n] * scale --------
__global__ __launch_bounds__(256) void transpose_cast_w(const float* __restrict__ W,
                                                        u16* __restrict__ WT, float scale) {
  __shared__ float tile[32][33];
  int kb = blockIdx.y * 32, nb = blockIdx.x * 32;
  int tx = threadIdx.x, ty = threadIdx.y;
#pragma unroll
  for (int i = 0; i < 4; i++)
    tile[ty + i * 8][tx] = W[(size_t)(kb + ty + i * 8) * D_EMB + nb + tx];
  __syncthreads();
#pragma unroll
  for (int i = 0; i < 4; i++)
    WT[(size_t)(nb + ty + i * 8) * D_EMB + kb + tx] = f2bf(tile[tx][ty + i * 8] * scale);
}

// -------- transpose V (bf16), pi-permuted columns within each 64-block --------
// position p holds key pi(p) where pi swaps bit fields: p=[H|g|a|v] -> key=[H|a|g|v]
// so key k is stored at p = (k&0x23) | ((k&0x0C)<<1) | ((k&0x10)>>2)
__global__ __launch_bounds__(256) void transpose_v(const u16* __restrict__ QKV,
                                                   u16* __restrict__ VT) {
  __shared__ u16 tile[32][33];
  int bh = blockIdx.z;
  int b = bh / NH, h = bh % NH;
  int sb = blockIdx.x * 32, db = blockIdx.y * 32;
  int tx = threadIdx.x, ty = threadIdx.y;
  const u16* src = QKV + (size_t)(b * SS) * E3 + 2 * D_EMB + h * DK;
  u16* dst = VT + (size_t)bh * DK * SS;
#pragma unroll
  for (int i = 0; i < 4; i++)
    tile[ty + i * 8][tx] = src[(size_t)(sb + ty + i * 8) * E3 + db + tx];
  __syncthreads();
  int s = sb + tx;
  int k6 = s & 63;
  int p = (s & ~63) | (k6 & 0x23) | ((k6 & 0x0C) << 1) | ((k6 & 0x10) >> 2);
#pragma unroll
  for (int i = 0; i < 4; i++)
    dst[(size_t)(db + ty + i * 8) * SS + p] = tile[tx][ty + i * 8];
}

// ---------------- bf16 GEMM, B given transposed: C[M][N] = A[M][K] @ Bt[N][K]^T ----------------
template <int OUTF32>
__global__ __launch_bounds__(256) void gemm_bt(const u16* __restrict__ A,
                                               const u16* __restrict__ Bt,
                                               void* __restrict__ Cout,
                                               int M, int N, int K, float scale) {
  __shared__ __align__(16) u16 As[128 * 32];
  __shared__ __align__(16) u16 Bs[128 * 32];
  int tid = threadIdx.x;
  int wave = tid >> 6, lane = tid & 63;
  int g = lane >> 4, nIdx = lane & 15;
  int m0 = blockIdx.y * 128, n0 = blockIdx.x * 128;
  int wm = (wave >> 1) * 64, wn = (wave & 1) * 64;

  f32x4 acc[4][4] = {};

  int row = tid >> 2, co = (tid & 3) * 8;
  int row2 = row + 64;

  for (int k0 = 0; k0 < K; k0 += 32) {
    __syncthreads();
    gload_lds16(A  + (size_t)(m0 + row)  * K + k0 + co, As + row  * 32 + co);
    gload_lds16(Bt + (size_t)(n0 + row)  * K + k0 + co, Bs + row  * 32 + co);
    gload_lds16(A  + (size_t)(m0 + row2) * K + k0 + co, As + row2 * 32 + co);
    gload_lds16(Bt + (size_t)(n0 + row2) * K + k0 + co, Bs + row2 * 32 + co);
    __syncthreads();

    bf16x8 af[4], bfr[4];
#pragma unroll
    for (int i = 0; i < 4; i++)
      af[i] = *(const bf16x8*)(As + (wm + i * 16 + nIdx) * 32 + g * 8);
#pragma unroll
    for (int j = 0; j < 4; j++)
      bfr[j] = *(const bf16x8*)(Bs + (wn + j * 16 + nIdx) * 32 + g * 8);
#pragma unroll
    for (int i = 0; i < 4; i++)
#pragma unroll
      for (int j = 0; j < 4; j++)
        acc[i][j] = mfma16(af[i], bfr[j], acc[i][j]);
  }

#pragma unroll
  for (int i = 0; i < 4; i++)
#pragma unroll
    for (int j = 0; j < 4; j++)
#pragma unroll
      for (int r = 0; r < 4; r++) {
        int rr = m0 + wm + i * 16 + g * 4 + r;
        int cc = n0 + wn + j * 16 + nIdx;
        float v = acc[i][j][r] * scale;
        if (OUTF32)
          ((float*)Cout)[(size_t)rr * N + cc] = v;
        else
          ((u16*)Cout)[(size_t)rr * N + cc] = f2bf(v);
      }
}

// ---------------- flash attention v3 ----------------
// S^T formulation; V columns pi-permuted so the P C-layout fragment IS the PV
// B-fragment of the same lane (zero cross-lane exchange). 32 q-rows per wave.
// grid (S/128, NH, B), block 256 (4 waves). Q pre-scaled by 0.125*log2(e).
__global__ __launch_bounds__(256, 3) void flash(const u16* __restrict__ QKV,
                                                const u16* __restrict__ VT,
                                                u16* __restrict__ O) {
  __shared__ __align__(16) u16 Ks[64 * 72];      // [kv][d], pad 8
  __shared__ __align__(16) u16 Vs[64 * 72];      // [d][kv-position], pad 8

  int b = blockIdx.z, h = blockIdx.y;
  int q0 = blockIdx.x * 128;
  int tid = threadIdx.x, w = tid >> 6, l = tid & 63;
  int g = l >> 4, n = l & 15;

  const u16* Qbase = QKV + (size_t)(b * SS + q0 + w * 32) * E3 + h * DK;
  const u16* Kbase = QKV + (size_t)(b * SS) * E3 + D_EMB + h * DK;
  const u16* VTb = VT + (size_t)(b * NH + h) * DK * SS;

  bf16x8 qf[2][2];
#pragma unroll
  for (int qg = 0; qg < 2; qg++)
#pragma unroll
    for (int hf = 0; hf < 2; hf++)
      qf[qg][hf] = *(const bf16x8*)(Qbase + (size_t)(qg * 16 + n) * E3 + hf * 32 + g * 8);

  f32x4 o_acc[2][4] = {};
  f32x4 l_acc[2] = {};
  u32x4 onev = {0x3F803F80u, 0x3F803F80u, 0x3F803F80u, 0x3F803F80u};
  bf16x8 aone = __builtin_bit_cast(bf16x8, onev);

  int sr = tid >> 3, sc = (tid & 7) * 8;     // staging: row sr/sr+32, 16B chunk sc
  const u16* Kg  = Kbase + (size_t)sr * E3 + sc;
  const u16* Kg2 = Kbase + (size_t)(sr + 32) * E3 + sc;
  const u16* Vg  = VTb + (size_t)sr * SS + sc;
  const u16* Vg2 = VTb + (size_t)(sr + 32) * SS + sc;
  u16* KsW  = Ks + sr * 72 + sc;
  u16* KsW2 = KsW + 32 * 72;
  u16* VsW  = Vs + sr * 72 + sc;
  u16* VsW2 = VsW + 32 * 72;

  // prefetch tile 0
  uint4 ka = *(const uint4*)Kg;
  uint4 kb = *(const uint4*)Kg2;
  uint4 va = *(const uint4*)Vg;
  uint4 vb = *(const uint4*)Vg2;

  for (int kt = 0; kt < SS / 64; kt++) {
    __syncthreads();
    *(uint4*)KsW  = ka;
    *(uint4*)KsW2 = kb;
    *(uint4*)VsW  = va;
    *(uint4*)VsW2 = vb;
    __syncthreads();

    if (kt < SS / 64 - 1) {      // prefetch next tile into regs (hidden under compute)
      size_t ko = (size_t)(kt + 1) * 64 * E3;
      int vo = (kt + 1) * 64;
      ka = *(const uint4*)(Kg + ko);
      kb = *(const uint4*)(Kg2 + ko);
      va = *(const uint4*)(Vg + vo);
      vb = *(const uint4*)(Vg2 + vo);
    }

    // S^T: C[qg][j] : lane holds P[q=n][key = 16j + 4g + r]
    f32x4 C[2][4];
#pragma unroll
    for (int j = 0; j < 4; j++) {
      bf16x8 kf0 = *(const bf16x8*)(Ks + (j * 16 + n) * 72 + g * 8);
      bf16x8 kf1 = *(const bf16x8*)(Ks + (j * 16 + n) * 72 + 32 + g * 8);
#pragma unroll
      for (int qg = 0; qg < 2; qg++) {
        f32x4 t = {};
        t = mfma16(kf0, qf[qg][0], t);
        t = mfma16(kf1, qf[qg][1], t);
        C[qg][j] = t;
      }
    }

    // P = exp2(S^T); lane-local pack into PV B-frags (pi-permuted V makes this exact)
    u32x4 Bw[2][2];
#pragma unroll
    for (int qg = 0; qg < 2; qg++) {
#pragma unroll
      for (int j = 0; j < 4; j++) {
        float p0 = exp2_fast(C[qg][j][0]);
        float p1 = exp2_fast(C[qg][j][1]);
        float p2 = exp2_fast(C[qg][j][2]);
        float p3 = exp2_fast(C[qg][j][3]);
        unsigned lo = __builtin_amdgcn_perm(__builtin_bit_cast(unsigned, p1),
                                            __builtin_bit_cast(unsigned, p0), 0x07060302u);
        unsigned hi = __builtin_amdgcn_perm(__builtin_bit_cast(unsigned, p3),
                                            __builtin_bit_cast(unsigned, p2), 0x07060302u);
        Bw[qg][j >> 1][(j & 1) * 2]     = lo;
        Bw[qg][j >> 1][(j & 1) * 2 + 1] = hi;
      }
      bf16x8 B0 = __builtin_bit_cast(bf16x8, Bw[qg][0]);
      bf16x8 B1 = __builtin_bit_cast(bf16x8, Bw[qg][1]);
      l_acc[qg] = mfma16(aone, B0, l_acc[qg]);
      l_acc[qg] = mfma16(aone, B1, l_acc[qg]);
    }

    // O^T += V^T P^T
#pragma unroll
    for (int dt = 0; dt < 4; dt++) {
      bf16x8 vf0 = *(const bf16x8*)(Vs + (dt * 16 + n) * 72 + g * 8);
      bf16x8 vf1 = *(const bf16x8*)(Vs + (dt * 16 + n) * 72 + 32 + g * 8);
#pragma unroll
      for (int qg = 0; qg < 2; qg++) {
        o_acc[qg][dt] = mfma16(vf0, __builtin_bit_cast(bf16x8, Bw[qg][0]), o_acc[qg][dt]);
        o_acc[qg][dt] = mfma16(vf1, __builtin_bit_cast(bf16x8, Bw[qg][1]), o_acc[qg][dt]);
      }
    }
  }

#pragma unroll
  for (int qg = 0; qg < 2; qg++) {
    float rl = rcp_fast(l_acc[qg][0]);
    u16* Ob = O + (size_t)(b * SS + q0 + w * 32 + qg * 16 + n) * D_EMB + h * DK;
#pragma unroll
    for (int dt = 0; dt < 4; dt++) {
      unsigned w0 = (unsigned)f2bf(o_acc[qg][dt][0] * rl) |
                    ((unsigned)f2bf(o_acc[qg][dt][1] * rl) << 16);
      unsigned w1 = (unsigned)f2bf(o_acc[qg][dt][2] * rl) |
                    ((unsigned)f2bf(o_acc[qg][dt][3] * rl) << 16);
      *(unsigned*)(Ob + dt * 16 + g * 4) = w0;
      *(unsigned*)(Ob + dt * 16 + g * 4 + 2) = w1;
    }
  }
}

extern "C" void kernel_launch(void* const* d_in, const int* in_sizes, int n_in,
                              void* d_out, int out_size, void* d_ws, size_t ws_size,
                              hipStream_t stream) {
  const float* X  = (const float*)d_in[0];
  const float* Wq = (const float*)d_in[1];
  const float* Wk = (const float*)d_in[2];
  const float* Wv = (const float*)d_in[3];
  const float* Wo = (const float*)d_in[4];
  float* out = (float*)d_out;

  u16* Xb    = (u16*)d_ws;                         // MM*D_EMB
  u16* WTqkv = Xb + (size_t)MM * D_EMB;            // E3*D_EMB
  u16* WoT   = WTqkv + (size_t)E3 * D_EMB;         // D_EMB*D_EMB
  u16* QKV   = WoT + (size_t)D_EMB * D_EMB;        // MM*E3
  u16* VT    = QKV + (size_t)MM * E3;              // NB*NH*DK*SS
  u16* Ob    = VT + (size_t)NB * NH * DK * SS;     // MM*D_EMB

  dim3 tb(32, 8);
  cast_kernel<<<(MM * D_EMB) / 1024, 256, 0, stream>>>(X, Xb, MM * D_EMB);
  // fold 1/sqrt(dk) * log2(e) into Wq: scores come out in log2 domain
  transpose_cast_w<<<dim3(24, 24), tb, 0, stream>>>(Wq, WTqkv, 0.125f * 1.4426950408889634f);
  transpose_cast_w<<<dim3(24, 24), tb, 0, stream>>>(Wk, WTqkv + (size_t)D_EMB * D_EMB, 1.0f);
  transpose_cast_w<<<dim3(24, 24), tb, 0, stream>>>(Wv, WTqkv + (size_t)2 * D_EMB * D_EMB, 1.0f);
  transpose_cast_w<<<dim3(24, 24), tb, 0, stream>>>(Wo, WoT, 1.0f);

  gemm_bt<0><<<dim3(E3 / 128, MM / 128), 256, 0, stream>>>(Xb, WTqkv, (void*)QKV,
                                                           MM, E3, D_EMB, 1.0f);
  transpose_v<<<dim3(SS / 32, 2, NB * NH), tb, 0, stream>>>(QKV, VT);
  flash<<<dim3(SS / 128, NH, NB), 256, 0, stream>>>(QKV, VT, Ob);
  gemm_bt<1><<<dim3(D_EMB / 128, MM / 128), 256, 0, stream>>>(Ob, WoT, (void*)out,
                                                              MM, D_EMB, D_EMB, 1.0f);
}